// Round 4
// baseline (308.052 us; speedup 1.0000x reference)
//
#include <hip/hip_runtime.h>
#include <hip/hip_fp16.h>

typedef _Float16 half8 __attribute__((ext_vector_type(8)));
typedef _Float16 half4 __attribute__((ext_vector_type(4)));
typedef float floatx4 __attribute__((ext_vector_type(4)));

// ---------------------------------------------------------------------------
// GCN: 3x (GCNConv + ReLU) + classifier, fp16 MFMA GEMMs + CSR gather agg.
//   L1: agg(x)[256] -> hgemm(W1)+b1+relu
//   L2: hgemm(W2) -> agg[512]+b2+relu
//   L3: hgemm(W3) -> agg[128]+b3+relu
//   clf hgemm(Wc)+bc -> fp32 out
// hgemm: 128x128 tile, BK=64, 4 waves, mfma_f32_16x16x32_f16.
//   - global_load_lds staging, pre-swizzled source (T2 XOR swizzle, conflicts=0)
//   - LDS double-buffer + L2-warm touch prefetch of tile t+2 (scratch LDS dst)
//   - counted vmcnt(2): touches stay in flight across barriers (T4)
//   - m204 bijective XCD-chunked 1D grid (A-strip locality, FETCH ~= A once)
// agg: half8/lane gather, unroll-4 (4 independent chains), no LDS/syncthreads.
// ---------------------------------------------------------------------------

__device__ __forceinline__ void gload_lds16(const _Float16* g, _Float16* l) {
    __builtin_amdgcn_global_load_lds(
        (__attribute__((address_space(1))) void*)(g),
        (__attribute__((address_space(3))) void*)(l), 16, 0, 0);
}
__device__ __forceinline__ void gload_lds4(const _Float16* g, _Float16* l) {
    __builtin_amdgcn_global_load_lds(
        (__attribute__((address_space(1))) void*)(g),
        (__attribute__((address_space(3))) void*)(l), 4, 0, 0);
}

// ---------------- graph prep ----------------
__global__ void init_kernel(float* __restrict__ deg, int* __restrict__ cnt,
                            int* __restrict__ pos, int n) {
    int i = blockIdx.x * blockDim.x + threadIdx.x;
    if (i < n) { deg[i] = 1.0f; cnt[i] = 0; pos[i] = 0; }
}

__global__ void hist_kernel(const int* __restrict__ dst, float* __restrict__ deg,
                            int* __restrict__ cnt, int E) {
    int e = blockIdx.x * blockDim.x + threadIdx.x;
    if (e < E) {
        int d = dst[e];
        atomicAdd(&deg[d], 1.0f);
        atomicAdd(&cnt[d], 1);
    }
}

__global__ void isd_kernel(const float* __restrict__ deg, float* __restrict__ isd, int n) {
    int i = blockIdx.x * blockDim.x + threadIdx.x;
    if (i < n) isd[i] = rsqrtf(deg[i]);
}

__global__ void scan_kernel(const int* __restrict__ cnt, int* __restrict__ row_ptr,
                            int n, int E) {
    __shared__ int part[1024];
    int t = threadIdx.x;
    int chunk = (n + 1023) >> 10;
    int beg = t * chunk, end = min(beg + chunk, n);
    int s = 0;
    for (int i = beg; i < end; ++i) s += cnt[i];
    part[t] = s;
    __syncthreads();
    for (int off = 1; off < 1024; off <<= 1) {
        int v = (t >= off) ? part[t - off] : 0;
        __syncthreads();
        part[t] += v;
        __syncthreads();
    }
    int run = part[t] - s;
    for (int i = beg; i < end; ++i) { row_ptr[i] = run; run += cnt[i]; }
    if (t == 0) row_ptr[n] = E;
}

__global__ void place_kernel(const int* __restrict__ src, const int* __restrict__ dst,
                             const float* __restrict__ isd, const int* __restrict__ row_ptr,
                             int* __restrict__ pos, int* __restrict__ s_src,
                             float* __restrict__ s_nrm, int E) {
    int e = blockIdx.x * blockDim.x + threadIdx.x;
    if (e < E) {
        int s = src[e], d = dst[e];
        int p = row_ptr[d] + atomicAdd(&pos[d], 1);
        s_src[p] = s;
        s_nrm[p] = isd[s] * isd[d];
    }
}

// ---------------- conversions ----------------
__global__ void f2h_kernel(const float4* __restrict__ in, half4* __restrict__ out, int n4) {
    int i = blockIdx.x * blockDim.x + threadIdx.x;
    if (i < n4) {
        float4 v = in[i];
        half4 o = { (_Float16)v.x, (_Float16)v.y, (_Float16)v.z, (_Float16)v.w };
        out[i] = o;
    }
}

// Wt[o][i] = W[i][o] as fp16; rows o in [fo, fo_pad) zero-filled.
__global__ void wtrans_kernel(const float* __restrict__ W, _Float16* __restrict__ Wt,
                              int fi, int fo, int fo_pad) {
    int idx = blockIdx.x * blockDim.x + threadIdx.x;
    if (idx >= fo_pad * fi) return;
    int o = idx / fi, i = idx - o * fi;
    Wt[idx] = (o < fo) ? (_Float16)W[(size_t)i * fo + o] : (_Float16)0.f;
}

// ---------------- aggregation: half8/lane, LPN lanes per node, unroll-4 -----
// out[i] = sum_e xin[src[e]]*nrm[e] + xin[i]*isd[i]^2 (+bias, relu)
template <int LPN, bool BIASRELU>
__global__ __launch_bounds__(256)
void aggv_kernel(const half8* __restrict__ xin, half8* __restrict__ xout,
                 const int* __restrict__ row_ptr, const int* __restrict__ s_src,
                 const float* __restrict__ s_nrm, const float* __restrict__ isd,
                 const float* __restrict__ bias, int n) {
    int t = blockIdx.x * blockDim.x + threadIdx.x;
    int i = t / LPN;
    int r = t % LPN;
    if (i >= n) return;
    float w = isd[i]; w *= w;
    half8 v = xin[(size_t)i * LPN + r];
    float a0[8], a1[8], a2[8], a3[8];
#pragma unroll
    for (int j = 0; j < 8; ++j) {
        a0[j] = (float)v[j] * w;
        a1[j] = 0.f; a2[j] = 0.f; a3[j] = 0.f;
    }
    int c = row_ptr[i], end = row_ptr[i + 1];
    for (; c + 4 <= end; c += 4) {
        int s0 = s_src[c], s1 = s_src[c + 1], s2 = s_src[c + 2], s3 = s_src[c + 3];
        float n0 = s_nrm[c], n1 = s_nrm[c + 1], n2 = s_nrm[c + 2], n3 = s_nrm[c + 3];
        half8 v0 = xin[(size_t)s0 * LPN + r];
        half8 v1 = xin[(size_t)s1 * LPN + r];
        half8 v2 = xin[(size_t)s2 * LPN + r];
        half8 v3 = xin[(size_t)s3 * LPN + r];
#pragma unroll
        for (int j = 0; j < 8; ++j) {
            a0[j] = fmaf((float)v0[j], n0, a0[j]);
            a1[j] = fmaf((float)v1[j], n1, a1[j]);
            a2[j] = fmaf((float)v2[j], n2, a2[j]);
            a3[j] = fmaf((float)v3[j], n3, a3[j]);
        }
    }
    for (; c < end; ++c) {
        int s0 = s_src[c];
        float n0 = s_nrm[c];
        half8 v0 = xin[(size_t)s0 * LPN + r];
#pragma unroll
        for (int j = 0; j < 8; ++j) a0[j] = fmaf((float)v0[j], n0, a0[j]);
    }
    half8 o;
#pragma unroll
    for (int j = 0; j < 8; ++j) {
        float s = (a0[j] + a1[j]) + (a2[j] + a3[j]);
        if (BIASRELU) s = fmaxf(s + bias[r * 8 + j], 0.f);
        o[j] = (_Float16)s;
    }
    xout[(size_t)i * LPN + r] = o;
}

// ---------------- fp16 MFMA GEMM ----------------
// C[M,Ncout] = A[Mpad,K] @ Bt[Npad,K]^T (+bias,+relu).
template <bool BIAS, bool RELU, bool OUT_HALF>
__global__ __launch_bounds__(256)
void hgemm_kernel(const _Float16* __restrict__ A, const _Float16* __restrict__ Bt,
                  const float* __restrict__ bias, void* __restrict__ C,
                  int M, int K, int Ncout, int ldc, int gy) {
    __shared__ _Float16 As[2][128 * 64];
    __shared__ _Float16 Bs[2][128 * 64];
    __shared__ _Float16 Tsc[512];   // touch scratch: 128 halfs (256B) per wave

    // m204 bijective XCD-chunked grid map
    int nwg = gridDim.x;
    int orig = blockIdx.x;
    int q = nwg >> 3, r = nwg & 7;
    int xcd = orig & 7, seq = orig >> 3;
    int wgid = (xcd < r ? xcd * (q + 1) : r * (q + 1) + (xcd - r) * q) + seq;
    int bx = wgid / gy, by = wgid % gy;

    const int tid = threadIdx.x;
    const int wave = tid >> 6, lane = tid & 63;
    const int l15 = lane & 15, lk = lane >> 4;
    const int wr = wave >> 1, wc = wave & 1;
    const int bm = bx * 128, bn = by * 128;

    // staging: chunk c = i*256+tid -> LDS halfs [c*8, c*8+8) (linear dest).
    // logical row = c>>3, k-group (c&7); source k pre-swizzled by row&7 (T2).
    const int srow = tid >> 3;
    const int sk_swz = (((tid & 7) ^ ((tid >> 3) & 7)) << 3);
    const _Float16* aSrc = A + (size_t)(bm + srow) * K + sk_swz;
    const _Float16* bSrc = Bt + (size_t)(bn + srow) * K + sk_swz;

    const int rowA = wr * 64 + l15;
    const int rowB = wc * 64 + l15;
    const int xorK = (l15 & 7) << 3;

    floatx4 acc[4][4] = {};

    auto STAGE = [&](int buf, int t) {
        int k0 = t << 6;
        _Float16* la = &As[buf][wave * 512];
        _Float16* lb = &Bs[buf][wave * 512];
#pragma unroll
        for (int i = 0; i < 4; ++i)
            gload_lds16(aSrc + k0 + (size_t)i * 32 * K, la + i * 2048);
#pragma unroll
        for (int i = 0; i < 4; ++i)
            gload_lds16(bSrc + k0 + (size_t)i * 32 * K, lb + i * 2048);
    };

    // L2-warm prefetch of tile t2: one dword per 64B line of the A/B slices.
    // 256 thr x 2 loads = 512 = 128 rows x 2 halves x 2 matrices.
    auto TOUCH = [&](int t2) {
        int k0 = t2 << 6;
        int rr = tid & 127;
        const _Float16* p = (tid < 128) ? (A + (size_t)(bm + rr) * K + k0)
                                        : (Bt + (size_t)(bn + rr) * K + k0);
        _Float16* dsc = Tsc + wave * 128;
        gload_lds4(p, dsc);
        gload_lds4(p + 32, dsc);
    };

    const int nt = K >> 6;
    STAGE(0, 0);
    if (nt > 1) {
        TOUCH(1);
        asm volatile("s_waitcnt vmcnt(2)" ::: "memory");
    } else {
        asm volatile("s_waitcnt vmcnt(0)" ::: "memory");
    }
    __builtin_amdgcn_s_barrier();

    for (int t = 0; t < nt; ++t) {
        int buf = t & 1;
        if (t + 1 < nt) STAGE(buf ^ 1, t + 1);
        bool touched = (t + 2 < nt);
        if (touched) TOUCH(t + 2);

#pragma unroll
        for (int ks = 0; ks < 2; ++ks) {
            const int kidx = ((lk << 3) + (ks << 5)) ^ xorK;
            half8 af[4], bf[4];
#pragma unroll
            for (int mi = 0; mi < 4; ++mi)
                af[mi] = *(const half8*)(&As[buf][(rowA + mi * 16) * 64 + kidx]);
#pragma unroll
            for (int ni = 0; ni < 4; ++ni)
                bf[ni] = *(const half8*)(&Bs[buf][(rowB + ni * 16) * 64 + kidx]);
#pragma unroll
            for (int mi = 0; mi < 4; ++mi)
#pragma unroll
                for (int ni = 0; ni < 4; ++ni)
                    acc[mi][ni] = __builtin_amdgcn_mfma_f32_16x16x32_f16(
                        af[mi], bf[ni], acc[mi][ni], 0, 0, 0);
        }
        // counted wait: stage loads (tile t+1) complete; touches (t+2) linger.
        if (touched) asm volatile("s_waitcnt vmcnt(2)" ::: "memory");
        else         asm volatile("s_waitcnt vmcnt(0)" ::: "memory");
        __builtin_amdgcn_s_barrier();
    }

    // epilogue: C/D layout col=lane&15, row=(lane>>4)*4+reg
#pragma unroll
    for (int mi = 0; mi < 4; ++mi) {
#pragma unroll
        for (int ni = 0; ni < 4; ++ni) {
            int col = bn + wc * 64 + ni * 16 + l15;
            int row0 = bm + wr * 64 + mi * 16 + lk * 4;
            floatx4 vv = acc[mi][ni];
            if (BIAS) {
                float bb = (col < Ncout) ? bias[col] : 0.f;
                vv[0] += bb; vv[1] += bb; vv[2] += bb; vv[3] += bb;
            }
            if (RELU) {
                vv[0] = fmaxf(vv[0], 0.f); vv[1] = fmaxf(vv[1], 0.f);
                vv[2] = fmaxf(vv[2], 0.f); vv[3] = fmaxf(vv[3], 0.f);
            }
            if (col < Ncout) {
#pragma unroll
                for (int rr = 0; rr < 4; ++rr) {
                    int row = row0 + rr;
                    if (row < M) {
                        if (OUT_HALF)
                            ((__half*)C)[(size_t)row * ldc + col] = __float2half(vv[rr]);
                        else
                            ((float*)C)[(size_t)row * ldc + col] = vv[rr];
                    }
                }
            }
        }
    }
}

extern "C" void kernel_launch(void* const* d_in, const int* in_sizes, int n_in,
                              void* d_out, int out_size, void* d_ws, size_t ws_size,
                              hipStream_t stream) {
    const float* x  = (const float*)d_in[0];
    const int*   ei = (const int*)d_in[1];
    const float* W1 = (const float*)d_in[2];
    const float* b1 = (const float*)d_in[3];
    const float* W2 = (const float*)d_in[4];
    const float* b2 = (const float*)d_in[5];
    const float* W3 = (const float*)d_in[6];
    const float* b3 = (const float*)d_in[7];
    const float* Wc = (const float*)d_in[8];
    const float* bc = (const float*)d_in[9];
    float* out = (float*)d_out;

    const int n = in_sizes[0] / 256;   // 20000
    const int E = in_sizes[1] / 2;     // 320000
    const int* src = ei;
    const int* dst = ei + E;
    const int Mpad = ((n + 127) / 128) * 128;  // 20096
    const int gx = Mpad / 128;                 // 157

    size_t off = 0;
    auto take = [&](size_t bytes) -> void* {
        void* p = (char*)d_ws + off;
        off += (bytes + 255) & ~(size_t)255;
        return p;
    };
    float* deg     = (float*)take((size_t)n * 4);
    float* isd     = (float*)take((size_t)n * 4);
    int*   cnt     = (int*)take((size_t)n * 4);
    int*   pos     = (int*)take((size_t)n * 4);
    int*   row_ptr = (int*)take((size_t)(n + 1) * 4);
    int*   s_src   = (int*)take((size_t)E * 4);
    float* s_nrm   = (float*)take((size_t)E * 4);
    _Float16* xh   = (_Float16*)take((size_t)n * 256 * 2);
    _Float16* a1h  = (_Float16*)take((size_t)Mpad * 256 * 2);
    _Float16* h1h  = (_Float16*)take((size_t)Mpad * 1024 * 2);
    _Float16* g2h  = (_Float16*)take((size_t)Mpad * 512 * 2);
    _Float16* a2h  = (_Float16*)take((size_t)Mpad * 512 * 2);
    _Float16* g3h  = (_Float16*)take((size_t)Mpad * 128 * 2);
    _Float16* a3h  = (_Float16*)take((size_t)Mpad * 128 * 2);
    _Float16* w1t  = (_Float16*)take((size_t)1024 * 256 * 2);
    _Float16* w2t  = (_Float16*)take((size_t)512 * 1024 * 2);
    _Float16* w3t  = (_Float16*)take((size_t)128 * 512 * 2);
    _Float16* wct  = (_Float16*)take((size_t)128 * 128 * 2);

    // --- graph prep ---
    init_kernel<<<(n + 255) / 256, 256, 0, stream>>>(deg, cnt, pos, n);
    hist_kernel<<<(E + 255) / 256, 256, 0, stream>>>(dst, deg, cnt, E);
    isd_kernel<<<(n + 255) / 256, 256, 0, stream>>>(deg, isd, n);
    scan_kernel<<<1, 1024, 0, stream>>>(cnt, row_ptr, n, E);
    place_kernel<<<(E + 255) / 256, 256, 0, stream>>>(src, dst, isd, row_ptr, pos,
                                                      s_src, s_nrm, E);

    // --- conversions ---
    int n4 = n * 256 / 4;
    f2h_kernel<<<(n4 + 255) / 256, 256, 0, stream>>>((const float4*)x, (half4*)xh, n4);
    wtrans_kernel<<<(1024 * 256 + 255) / 256, 256, 0, stream>>>(W1, w1t, 256, 1024, 1024);
    wtrans_kernel<<<(512 * 1024 + 255) / 256, 256, 0, stream>>>(W2, w2t, 1024, 512, 512);
    wtrans_kernel<<<(128 * 512 + 255) / 256, 256, 0, stream>>>(W3, w3t, 512, 128, 128);
    wtrans_kernel<<<(128 * 128 + 255) / 256, 256, 0, stream>>>(Wc, wct, 128, 64, 128);

    // --- Layer 1: agg(xh)[256] -> GEMM(W1)+b1+relu -> h1h [n,1024] ---
    aggv_kernel<32, false><<<(n * 32 + 255) / 256, 256, 0, stream>>>(
        (const half8*)xh, (half8*)a1h, row_ptr, s_src, s_nrm, isd, nullptr, n);
    hgemm_kernel<true, true, true><<<gx * 8, 256, 0, stream>>>(
        a1h, w1t, b1, h1h, n, 256, 1024, 1024, 8);

    // --- Layer 2: GEMM(W2) -> agg[512]+b2+relu -> a2h ---
    hgemm_kernel<false, false, true><<<gx * 4, 256, 0, stream>>>(
        h1h, w2t, nullptr, g2h, n, 1024, 512, 512, 4);
    aggv_kernel<64, true><<<(n * 64 + 255) / 256, 256, 0, stream>>>(
        (const half8*)g2h, (half8*)a2h, row_ptr, s_src, s_nrm, isd, b2, n);

    // --- Layer 3: GEMM(W3) -> agg[128]+b3+relu -> a3h ---
    hgemm_kernel<false, false, true><<<gx * 1, 256, 0, stream>>>(
        a2h, w3t, nullptr, g3h, n, 512, 128, 128, 1);
    aggv_kernel<16, true><<<(n * 16 + 255) / 256, 256, 0, stream>>>(
        (const half8*)g3h, (half8*)a3h, row_ptr, s_src, s_nrm, isd, b3, n);

    // --- Classifier: GEMM(Wc)+bc -> out [n,64] fp32 ---
    hgemm_kernel<true, false, false><<<gx * 1, 256, 0, stream>>>(
        a3h, wct, bc, out, n, 128, 64, 64, 1);
}

// Round 5
// 282.801 us; speedup vs baseline: 1.0893x; 1.0893x over previous
//
#include <hip/hip_runtime.h>
#include <hip/hip_fp16.h>

typedef _Float16 half8 __attribute__((ext_vector_type(8)));
typedef _Float16 half4 __attribute__((ext_vector_type(4)));
typedef float floatx4 __attribute__((ext_vector_type(4)));

// ---------------------------------------------------------------------------
// GCN: 3x (GCNConv + ReLU) + classifier, fp16 MFMA GEMMs + CSR gather agg.
//   L1: agg(x)[256] -> hgemm(W1)+b1+relu
//   L2: hgemm(W2) -> agg[512]+b2+relu
//   L3: hgemm(W3) -> agg[128]+b3+relu
//   clf hgemm(Wc)+bc -> fp32 out
// hgemm: 128x128 tile, BK=64, 4 waves, mfma_f32_16x16x32_f16.
//   - T2 XOR swizzle via pre-swizzled global source (bank conflicts = 0)
//   - depth-2 pipeline: tile t+1 in regs (ds_write into freed buffer),
//     tile t+2 issued to regs at step start; counted vmcnt(8) (T4)
//   - m204 bijective XCD-chunked 1D grid (A-strip locality)
// agg: half8/lane gather, unroll-4 independent chains, no LDS/syncthreads.
// ---------------------------------------------------------------------------

__device__ __forceinline__ void gload_lds16(const _Float16* g, _Float16* l) {
    __builtin_amdgcn_global_load_lds(
        (__attribute__((address_space(1))) void*)(g),
        (__attribute__((address_space(3))) void*)(l), 16, 0, 0);
}

// ---------------- graph prep ----------------
__global__ void init_kernel(int* __restrict__ cnt, int* __restrict__ pos, int n) {
    int i = blockIdx.x * blockDim.x + threadIdx.x;
    if (i < n) { cnt[i] = 0; pos[i] = 0; }
}

__global__ void hist_kernel(const int* __restrict__ dst, int* __restrict__ cnt, int E) {
    int e = blockIdx.x * blockDim.x + threadIdx.x;
    if (e < E) atomicAdd(&cnt[dst[e]], 1);
}

__global__ void isd_kernel(const int* __restrict__ cnt, float* __restrict__ isd, int n) {
    int i = blockIdx.x * blockDim.x + threadIdx.x;
    if (i < n) isd[i] = rsqrtf((float)(cnt[i] + 1));  // +1 self loop
}

__global__ void scan_kernel(const int* __restrict__ cnt, int* __restrict__ row_ptr,
                            int n, int E) {
    __shared__ int part[1024];
    int t = threadIdx.x;
    int chunk = (n + 1023) >> 10;
    int beg = t * chunk, end = min(beg + chunk, n);
    int s = 0;
    for (int i = beg; i < end; ++i) s += cnt[i];
    part[t] = s;
    __syncthreads();
    for (int off = 1; off < 1024; off <<= 1) {
        int v = (t >= off) ? part[t - off] : 0;
        __syncthreads();
        part[t] += v;
        __syncthreads();
    }
    int run = part[t] - s;
    for (int i = beg; i < end; ++i) { row_ptr[i] = run; run += cnt[i]; }
    if (t == 0) row_ptr[n] = E;
}

__global__ void place_kernel(const int* __restrict__ src, const int* __restrict__ dst,
                             const float* __restrict__ isd, const int* __restrict__ row_ptr,
                             int* __restrict__ pos, int* __restrict__ s_src,
                             float* __restrict__ s_nrm, int E) {
    int e = blockIdx.x * blockDim.x + threadIdx.x;
    if (e < E) {
        int s = src[e], d = dst[e];
        int p = row_ptr[d] + atomicAdd(&pos[d], 1);
        s_src[p] = s;
        s_nrm[p] = isd[s] * isd[d];
    }
}

// ---------------- conversions ----------------
__global__ void f2h_kernel(const float4* __restrict__ in, half4* __restrict__ out, int n4) {
    int i = blockIdx.x * blockDim.x + threadIdx.x;
    if (i < n4) {
        float4 v = in[i];
        half4 o = { (_Float16)v.x, (_Float16)v.y, (_Float16)v.z, (_Float16)v.w };
        out[i] = o;
    }
}

// Wt[o][i] = W[i][o] as fp16; rows o in [fo, fo_pad) zero-filled.
__global__ void wtrans_kernel(const float* __restrict__ W, _Float16* __restrict__ Wt,
                              int fi, int fo, int fo_pad) {
    int idx = blockIdx.x * blockDim.x + threadIdx.x;
    if (idx >= fo_pad * fi) return;
    int o = idx / fi, i = idx - o * fi;
    Wt[idx] = (o < fo) ? (_Float16)W[(size_t)i * fo + o] : (_Float16)0.f;
}

// ---------------- aggregation: half8/lane, LPN lanes per node, unroll-4 -----
template <int LPN, bool BIASRELU>
__global__ __launch_bounds__(256)
void aggv_kernel(const half8* __restrict__ xin, half8* __restrict__ xout,
                 const int* __restrict__ row_ptr, const int* __restrict__ s_src,
                 const float* __restrict__ s_nrm, const float* __restrict__ isd,
                 const float* __restrict__ bias, int n) {
    int t = blockIdx.x * blockDim.x + threadIdx.x;
    int i = t / LPN;
    int r = t % LPN;
    if (i >= n) return;
    float w = isd[i]; w *= w;
    half8 v = xin[(size_t)i * LPN + r];
    float a0[8], a1[8], a2[8], a3[8];
#pragma unroll
    for (int j = 0; j < 8; ++j) {
        a0[j] = (float)v[j] * w;
        a1[j] = 0.f; a2[j] = 0.f; a3[j] = 0.f;
    }
    int c = row_ptr[i], end = row_ptr[i + 1];
    for (; c + 4 <= end; c += 4) {
        int s0 = s_src[c], s1 = s_src[c + 1], s2 = s_src[c + 2], s3 = s_src[c + 3];
        float n0 = s_nrm[c], n1 = s_nrm[c + 1], n2 = s_nrm[c + 2], n3 = s_nrm[c + 3];
        half8 v0 = xin[(size_t)s0 * LPN + r];
        half8 v1 = xin[(size_t)s1 * LPN + r];
        half8 v2 = xin[(size_t)s2 * LPN + r];
        half8 v3 = xin[(size_t)s3 * LPN + r];
#pragma unroll
        for (int j = 0; j < 8; ++j) {
            a0[j] = fmaf((float)v0[j], n0, a0[j]);
            a1[j] = fmaf((float)v1[j], n1, a1[j]);
            a2[j] = fmaf((float)v2[j], n2, a2[j]);
            a3[j] = fmaf((float)v3[j], n3, a3[j]);
        }
    }
    for (; c < end; ++c) {
        int s0 = s_src[c];
        float n0 = s_nrm[c];
        half8 v0 = xin[(size_t)s0 * LPN + r];
#pragma unroll
        for (int j = 0; j < 8; ++j) a0[j] = fmaf((float)v0[j], n0, a0[j]);
    }
    half8 o;
#pragma unroll
    for (int j = 0; j < 8; ++j) {
        float s = (a0[j] + a1[j]) + (a2[j] + a3[j]);
        if (BIASRELU) s = fmaxf(s + bias[r * 8 + j], 0.f);
        o[j] = (_Float16)s;
    }
    xout[(size_t)i * LPN + r] = o;
}

// ---------------- fp16 MFMA GEMM, depth-2 reg pipeline ----------------
// C[M,Ncout] = A[Mpad,K] @ Bt[Npad,K]^T (+bias,+relu).
template <bool BIAS, bool RELU, bool OUT_HALF>
__global__ __launch_bounds__(256)
void hgemm_kernel(const _Float16* __restrict__ A, const _Float16* __restrict__ Bt,
                  const float* __restrict__ bias, void* __restrict__ C,
                  int M, int K, int Ncout, int ldc, int gy) {
    __shared__ _Float16 As[2][128 * 64];
    __shared__ _Float16 Bs[2][128 * 64];

    // m204 bijective XCD-chunked grid map
    int nwg = gridDim.x;
    int orig = blockIdx.x;
    int q = nwg >> 3, r = nwg & 7;
    int xcd = orig & 7, seq = orig >> 3;
    int wgid = (xcd < r ? xcd * (q + 1) : r * (q + 1) + (xcd - r) * q) + seq;
    int bx = wgid / gy, by = wgid % gy;

    const int tid = threadIdx.x;
    const int wave = tid >> 6, lane = tid & 63;
    const int l15 = lane & 15, lk = lane >> 4;
    const int wr = wave >> 1, wc = wave & 1;
    const int bm = bx * 128, bn = by * 128;

    // staging: chunk c = i*256+tid covers row (c>>3) = i*32 + (tid>>3),
    // k-group (c&7) = (tid&7); source k pre-swizzled by row&7 (T2).
    // LDS dest linear at halfs c*8 (matches gload_lds wave-uniform+lane*16B).
    const int sk_swz = (((tid & 7) ^ ((tid >> 3) & 7)) << 3);
    const _Float16* aSrc = A + (size_t)(bm + (tid >> 3)) * K + sk_swz;
    const _Float16* bSrc = Bt + (size_t)(bn + (tid >> 3)) * K + sk_swz;

    const int rowA = wr * 64 + l15;
    const int rowB = wc * 64 + l15;
    const int xorK = (l15 & 7) << 3;

    floatx4 acc[4][4] = {};
    half8 ra0[4], rb0[4], ra1[4], rb1[4];   // two named reg sets (rule #20)

    auto STAGE_LDS = [&](int buf, int t) {   // tile t -> LDS via gload_lds
        int k0 = t << 6;
        _Float16* la = &As[buf][wave * 512];
        _Float16* lb = &Bs[buf][wave * 512];
#pragma unroll
        for (int i = 0; i < 4; ++i)
            gload_lds16(aSrc + k0 + (size_t)i * 32 * K, la + i * 2048);
#pragma unroll
        for (int i = 0; i < 4; ++i)
            gload_lds16(bSrc + k0 + (size_t)i * 32 * K, lb + i * 2048);
    };

    auto LOADR = [&](int t, half8 (&ra)[4], half8 (&rb)[4]) {  // tile t -> regs
        int k0 = t << 6;
#pragma unroll
        for (int i = 0; i < 4; ++i)
            ra[i] = *(const half8*)(aSrc + k0 + (size_t)i * 32 * K);
#pragma unroll
        for (int i = 0; i < 4; ++i)
            rb[i] = *(const half8*)(bSrc + k0 + (size_t)i * 32 * K);
    };

    auto WRITE = [&](int buf, half8 (&ra)[4], half8 (&rb)[4]) {  // regs -> LDS
#pragma unroll
        for (int i = 0; i < 4; ++i)
            *(half8*)(&As[buf][(i * 256 + tid) * 8]) = ra[i];
#pragma unroll
        for (int i = 0; i < 4; ++i)
            *(half8*)(&Bs[buf][(i * 256 + tid) * 8]) = rb[i];
    };

    auto COMPUTE = [&](int buf) {
#pragma unroll
        for (int ks = 0; ks < 2; ++ks) {
            const int kidx = ((lk << 3) + (ks << 5)) ^ xorK;
            half8 af[4], bf[4];
#pragma unroll
            for (int mi = 0; mi < 4; ++mi)
                af[mi] = *(const half8*)(&As[buf][(rowA + mi * 16) * 64 + kidx]);
#pragma unroll
            for (int ni = 0; ni < 4; ++ni)
                bf[ni] = *(const half8*)(&Bs[buf][(rowB + ni * 16) * 64 + kidx]);
#pragma unroll
            for (int mi = 0; mi < 4; ++mi)
#pragma unroll
                for (int ni = 0; ni < 4; ++ni)
                    acc[mi][ni] = __builtin_amdgcn_mfma_f32_16x16x32_f16(
                        af[mi], bf[ni], acc[mi][ni], 0, 0, 0);
        }
    };

    const int nt = K >> 6;   // >= 2 for all layers here

    // prologue: tile 0 -> LDS(buf0); tile 1 -> reg set1
    STAGE_LDS(0, 0);
    if (nt > 1) {
        LOADR(1, ra1, rb1);
        asm volatile("s_waitcnt vmcnt(8)" ::: "memory");  // stage(0) done; L(1) in flight
    } else {
        asm volatile("s_waitcnt vmcnt(0)" ::: "memory");
    }
    __builtin_amdgcn_s_barrier();

    for (int t = 0; t < nt; t += 2) {
        // ---- even substep: compute tile t (buf0) ----
        {
            bool ld = (t + 2 < nt), wrt = (t + 1 < nt);
            if (ld) LOADR(t + 2, ra0, rb0);               // issue into set0
            if (wrt) {
                if (ld) asm volatile("s_waitcnt vmcnt(8)" ::: "memory");  // L(t+1) done
                else    asm volatile("s_waitcnt vmcnt(0)" ::: "memory");
                WRITE(1, ra1, rb1);                       // t+1 -> buf1
            }
            COMPUTE(0);
            asm volatile("s_waitcnt lgkmcnt(0)" ::: "memory");
            __builtin_amdgcn_s_barrier();
        }
        // ---- odd substep: compute tile t+1 (buf1) ----
        if (t + 1 < nt) {
            bool ld = (t + 3 < nt), wrt = (t + 2 < nt);
            if (ld) LOADR(t + 3, ra1, rb1);               // issue into set1
            if (wrt) {
                if (ld) asm volatile("s_waitcnt vmcnt(8)" ::: "memory");  // L(t+2) done
                else    asm volatile("s_waitcnt vmcnt(0)" ::: "memory");
                WRITE(0, ra0, rb0);                       // t+2 -> buf0
            }
            COMPUTE(1);
            asm volatile("s_waitcnt lgkmcnt(0)" ::: "memory");
            __builtin_amdgcn_s_barrier();
        }
    }

    // epilogue: C/D layout col=lane&15, row=(lane>>4)*4+reg
#pragma unroll
    for (int mi = 0; mi < 4; ++mi) {
#pragma unroll
        for (int ni = 0; ni < 4; ++ni) {
            int col = bn + wc * 64 + ni * 16 + l15;
            int row0 = bm + wr * 64 + mi * 16 + lk * 4;
            floatx4 vv = acc[mi][ni];
            if (BIAS) {
                float bb = (col < Ncout) ? bias[col] : 0.f;
                vv[0] += bb; vv[1] += bb; vv[2] += bb; vv[3] += bb;
            }
            if (RELU) {
                vv[0] = fmaxf(vv[0], 0.f); vv[1] = fmaxf(vv[1], 0.f);
                vv[2] = fmaxf(vv[2], 0.f); vv[3] = fmaxf(vv[3], 0.f);
            }
            if (col < Ncout) {
#pragma unroll
                for (int rr = 0; rr < 4; ++rr) {
                    int row = row0 + rr;
                    if (row < M) {
                        if (OUT_HALF)
                            ((__half*)C)[(size_t)row * ldc + col] = __float2half(vv[rr]);
                        else
                            ((float*)C)[(size_t)row * ldc + col] = vv[rr];
                    }
                }
            }
        }
    }
}

extern "C" void kernel_launch(void* const* d_in, const int* in_sizes, int n_in,
                              void* d_out, int out_size, void* d_ws, size_t ws_size,
                              hipStream_t stream) {
    const float* x  = (const float*)d_in[0];
    const int*   ei = (const int*)d_in[1];
    const float* W1 = (const float*)d_in[2];
    const float* b1 = (const float*)d_in[3];
    const float* W2 = (const float*)d_in[4];
    const float* b2 = (const float*)d_in[5];
    const float* W3 = (const float*)d_in[6];
    const float* b3 = (const float*)d_in[7];
    const float* Wc = (const float*)d_in[8];
    const float* bc = (const float*)d_in[9];
    float* out = (float*)d_out;

    const int n = in_sizes[0] / 256;   // 20000
    const int E = in_sizes[1] / 2;     // 320000
    const int* src = ei;
    const int* dst = ei + E;
    const int Mpad = ((n + 127) / 128) * 128;  // 20096
    const int gx = Mpad / 128;                 // 157

    size_t off = 0;
    auto take = [&](size_t bytes) -> void* {
        void* p = (char*)d_ws + off;
        off += (bytes + 255) & ~(size_t)255;
        return p;
    };
    float* isd     = (float*)take((size_t)n * 4);
    int*   cnt     = (int*)take((size_t)n * 4);
    int*   pos     = (int*)take((size_t)n * 4);
    int*   row_ptr = (int*)take((size_t)(n + 1) * 4);
    int*   s_src   = (int*)take((size_t)E * 4);
    float* s_nrm   = (float*)take((size_t)E * 4);
    _Float16* xh   = (_Float16*)take((size_t)n * 256 * 2);
    _Float16* a1h  = (_Float16*)take((size_t)Mpad * 256 * 2);
    _Float16* h1h  = (_Float16*)take((size_t)Mpad * 1024 * 2);
    _Float16* g2h  = (_Float16*)take((size_t)Mpad * 512 * 2);
    _Float16* a2h  = (_Float16*)take((size_t)Mpad * 512 * 2);
    _Float16* g3h  = (_Float16*)take((size_t)Mpad * 128 * 2);
    _Float16* a3h  = (_Float16*)take((size_t)Mpad * 128 * 2);
    _Float16* w1t  = (_Float16*)take((size_t)1024 * 256 * 2);
    _Float16* w2t  = (_Float16*)take((size_t)512 * 1024 * 2);
    _Float16* w3t  = (_Float16*)take((size_t)128 * 512 * 2);
    _Float16* wct  = (_Float16*)take((size_t)128 * 128 * 2);

    // --- graph prep ---
    init_kernel<<<(n + 255) / 256, 256, 0, stream>>>(cnt, pos, n);
    hist_kernel<<<(E + 255) / 256, 256, 0, stream>>>(dst, cnt, E);
    isd_kernel<<<(n + 255) / 256, 256, 0, stream>>>(cnt, isd, n);
    scan_kernel<<<1, 1024, 0, stream>>>(cnt, row_ptr, n, E);
    place_kernel<<<(E + 255) / 256, 256, 0, stream>>>(src, dst, isd, row_ptr, pos,
                                                      s_src, s_nrm, E);

    // --- conversions ---
    int n4 = n * 256 / 4;
    f2h_kernel<<<(n4 + 255) / 256, 256, 0, stream>>>((const float4*)x, (half4*)xh, n4);
    wtrans_kernel<<<(1024 * 256 + 255) / 256, 256, 0, stream>>>(W1, w1t, 256, 1024, 1024);
    wtrans_kernel<<<(512 * 1024 + 255) / 256, 256, 0, stream>>>(W2, w2t, 1024, 512, 512);
    wtrans_kernel<<<(128 * 512 + 255) / 256, 256, 0, stream>>>(W3, w3t, 512, 128, 128);
    wtrans_kernel<<<(128 * 128 + 255) / 256, 256, 0, stream>>>(Wc, wct, 128, 64, 128);

    // --- Layer 1: agg(xh)[256] -> GEMM(W1)+b1+relu -> h1h [n,1024] ---
    aggv_kernel<32, false><<<(n * 32 + 255) / 256, 256, 0, stream>>>(
        (const half8*)xh, (half8*)a1h, row_ptr, s_src, s_nrm, isd, nullptr, n);
    hgemm_kernel<true, true, true><<<gx * 8, 256, 0, stream>>>(
        a1h, w1t, b1, h1h, n, 256, 1024, 1024, 8);

    // --- Layer 2: GEMM(W2) -> agg[512]+b2+relu -> a2h ---
    hgemm_kernel<false, false, true><<<gx * 4, 256, 0, stream>>>(
        h1h, w2t, nullptr, g2h, n, 1024, 512, 512, 4);
    aggv_kernel<64, true><<<(n * 64 + 255) / 256, 256, 0, stream>>>(
        (const half8*)g2h, (half8*)a2h, row_ptr, s_src, s_nrm, isd, b2, n);

    // --- Layer 3: GEMM(W3) -> agg[128]+b3+relu -> a3h ---
    hgemm_kernel<false, false, true><<<gx * 1, 256, 0, stream>>>(
        a2h, w3t, nullptr, g3h, n, 512, 128, 128, 1);
    aggv_kernel<16, true><<<(n * 16 + 255) / 256, 256, 0, stream>>>(
        (const half8*)g3h, (half8*)a3h, row_ptr, s_src, s_nrm, isd, b3, n);

    // --- Classifier: GEMM(Wc)+bc -> out [n,64] fp32 ---
    hgemm_kernel<true, false, false><<<gx * 1, 256, 0, stream>>>(
        a3h, wct, bc, out, n, 128, 64, 64, 1);
}

// Round 6
// 242.204 us; speedup vs baseline: 1.2719x; 1.1676x over previous
//
#include <hip/hip_runtime.h>
#include <hip/hip_fp16.h>

typedef _Float16 half8 __attribute__((ext_vector_type(8)));
typedef _Float16 half4 __attribute__((ext_vector_type(4)));
typedef float floatx4 __attribute__((ext_vector_type(4)));

// ---------------------------------------------------------------------------
// GCN: 3x (GCNConv + ReLU) + classifier, fp16 MFMA GEMMs + CSR gather agg.
//   L1: agg(x)[256] -> hgemm(W1)+b1+relu
//   L2: hgemm(W2) -> agg[512]+b2+relu
//   L3: hgemm(W3) -> agg[128]+b3+relu
//   clf hgemm(Wc)+bc -> fp32 out
// hgemm: 128x64 tile, BK=64, 4 waves (2x2; each wave 64x32 = 4x2 frags),
//   single 24KB LDS buffer, plain 2-barrier loop (m97 structure: TLP via
//   4-6 blocks/CU hides staging latency; R4/R5 showed in-block pipelining
//   is null in this regime).
//   - T2 XOR swizzle via pre-swizzled global source (bank conflicts = 0)
//   - m204 bijective XCD-chunked 1D grid (A-strip L2 locality)
// agg: half8/lane gather, unroll-8 edge chains, no LDS/syncthreads.
// ---------------------------------------------------------------------------

__device__ __forceinline__ void gload_lds16(const _Float16* g, _Float16* l) {
    __builtin_amdgcn_global_load_lds(
        (__attribute__((address_space(1))) void*)(g),
        (__attribute__((address_space(3))) void*)(l), 16, 0, 0);
}

// ---------------- graph prep ----------------
__global__ void init_kernel(int* __restrict__ cnt, int* __restrict__ pos, int n) {
    int i = blockIdx.x * blockDim.x + threadIdx.x;
    if (i < n) { cnt[i] = 0; pos[i] = 0; }
}

__global__ void hist_kernel(const int* __restrict__ dst, int* __restrict__ cnt, int E) {
    int e = blockIdx.x * blockDim.x + threadIdx.x;
    if (e < E) atomicAdd(&cnt[dst[e]], 1);
}

__global__ void isd_kernel(const int* __restrict__ cnt, float* __restrict__ isd, int n) {
    int i = blockIdx.x * blockDim.x + threadIdx.x;
    if (i < n) isd[i] = rsqrtf((float)(cnt[i] + 1));  // +1 self loop
}

__global__ void scan_kernel(const int* __restrict__ cnt, int* __restrict__ row_ptr,
                            int n, int E) {
    __shared__ int part[1024];
    int t = threadIdx.x;
    int chunk = (n + 1023) >> 10;
    int beg = t * chunk, end = min(beg + chunk, n);
    int s = 0;
    for (int i = beg; i < end; ++i) s += cnt[i];
    part[t] = s;
    __syncthreads();
    for (int off = 1; off < 1024; off <<= 1) {
        int v = (t >= off) ? part[t - off] : 0;
        __syncthreads();
        part[t] += v;
        __syncthreads();
    }
    int run = part[t] - s;
    for (int i = beg; i < end; ++i) { row_ptr[i] = run; run += cnt[i]; }
    if (t == 0) row_ptr[n] = E;
}

__global__ void place_kernel(const int* __restrict__ src, const int* __restrict__ dst,
                             const float* __restrict__ isd, const int* __restrict__ row_ptr,
                             int* __restrict__ pos, int* __restrict__ s_src,
                             float* __restrict__ s_nrm, int E) {
    int e = blockIdx.x * blockDim.x + threadIdx.x;
    if (e < E) {
        int s = src[e], d = dst[e];
        int p = row_ptr[d] + atomicAdd(&pos[d], 1);
        s_src[p] = s;
        s_nrm[p] = isd[s] * isd[d];
    }
}

// ---------------- conversions ----------------
__global__ void f2h_kernel(const float4* __restrict__ in, half4* __restrict__ out, int n4) {
    int i = blockIdx.x * blockDim.x + threadIdx.x;
    if (i < n4) {
        float4 v = in[i];
        half4 o = { (_Float16)v.x, (_Float16)v.y, (_Float16)v.z, (_Float16)v.w };
        out[i] = o;
    }
}

// Wt[o][i] = W[i][o] as fp16; rows o in [fo, fo_pad) zero-filled.
__global__ void wtrans_kernel(const float* __restrict__ W, _Float16* __restrict__ Wt,
                              int fi, int fo, int fo_pad) {
    int idx = blockIdx.x * blockDim.x + threadIdx.x;
    if (idx >= fo_pad * fi) return;
    int o = idx / fi, i = idx - o * fi;
    Wt[idx] = (o < fo) ? (_Float16)W[(size_t)i * fo + o] : (_Float16)0.f;
}

// ---------------- aggregation: half8/lane, LPN lanes per node, unroll-8 -----
// out[i] = sum_e xin[src[e]]*nrm[e] + xin[i]*isd[i]^2 (+bias, relu)
template <int LPN, bool BIASRELU>
__global__ __launch_bounds__(256)
void aggv_kernel(const half8* __restrict__ xin, half8* __restrict__ xout,
                 const int* __restrict__ row_ptr, const int* __restrict__ s_src,
                 const float* __restrict__ s_nrm, const float* __restrict__ isd,
                 const float* __restrict__ bias, int n) {
    int t = blockIdx.x * blockDim.x + threadIdx.x;
    int i = t / LPN;
    int r = t % LPN;
    if (i >= n) return;
    float w = isd[i]; w *= w;
    half8 v = xin[(size_t)i * LPN + r];
    float a0[8], a1[8], a2[8], a3[8];
#pragma unroll
    for (int j = 0; j < 8; ++j) {
        a0[j] = (float)v[j] * w;
        a1[j] = 0.f; a2[j] = 0.f; a3[j] = 0.f;
    }
    int c = row_ptr[i], end = row_ptr[i + 1];
    for (; c + 8 <= end; c += 8) {
        int s0 = s_src[c],     s1 = s_src[c + 1], s2 = s_src[c + 2], s3 = s_src[c + 3];
        int s4 = s_src[c + 4], s5 = s_src[c + 5], s6 = s_src[c + 6], s7 = s_src[c + 7];
        float n0 = s_nrm[c],     n1 = s_nrm[c + 1], n2 = s_nrm[c + 2], n3 = s_nrm[c + 3];
        float n4 = s_nrm[c + 4], n5 = s_nrm[c + 5], n6 = s_nrm[c + 6], n7 = s_nrm[c + 7];
        half8 v0 = xin[(size_t)s0 * LPN + r];
        half8 v1 = xin[(size_t)s1 * LPN + r];
        half8 v2 = xin[(size_t)s2 * LPN + r];
        half8 v3 = xin[(size_t)s3 * LPN + r];
        half8 v4 = xin[(size_t)s4 * LPN + r];
        half8 v5 = xin[(size_t)s5 * LPN + r];
        half8 v6 = xin[(size_t)s6 * LPN + r];
        half8 v7 = xin[(size_t)s7 * LPN + r];
#pragma unroll
        for (int j = 0; j < 8; ++j) {
            a0[j] = fmaf((float)v0[j], n0, a0[j]);
            a1[j] = fmaf((float)v1[j], n1, a1[j]);
            a2[j] = fmaf((float)v2[j], n2, a2[j]);
            a3[j] = fmaf((float)v3[j], n3, a3[j]);
            a0[j] = fmaf((float)v4[j], n4, a0[j]);
            a1[j] = fmaf((float)v5[j], n5, a1[j]);
            a2[j] = fmaf((float)v6[j], n6, a2[j]);
            a3[j] = fmaf((float)v7[j], n7, a3[j]);
        }
    }
    for (; c + 2 <= end; c += 2) {
        int s0 = s_src[c], s1 = s_src[c + 1];
        float n0 = s_nrm[c], n1 = s_nrm[c + 1];
        half8 v0 = xin[(size_t)s0 * LPN + r];
        half8 v1 = xin[(size_t)s1 * LPN + r];
#pragma unroll
        for (int j = 0; j < 8; ++j) {
            a0[j] = fmaf((float)v0[j], n0, a0[j]);
            a1[j] = fmaf((float)v1[j], n1, a1[j]);
        }
    }
    if (c < end) {
        int s0 = s_src[c];
        float n0 = s_nrm[c];
        half8 v0 = xin[(size_t)s0 * LPN + r];
#pragma unroll
        for (int j = 0; j < 8; ++j) a0[j] = fmaf((float)v0[j], n0, a0[j]);
    }
    half8 o;
#pragma unroll
    for (int j = 0; j < 8; ++j) {
        float s = (a0[j] + a1[j]) + (a2[j] + a3[j]);
        if (BIASRELU) s = fmaxf(s + bias[r * 8 + j], 0.f);
        o[j] = (_Float16)s;
    }
    xout[(size_t)i * LPN + r] = o;
}

// ---------------- fp16 MFMA GEMM, 128x64 tile, single-buffer m97 loop -------
// C[M,Ncout] = A[Mpad,K] @ Bt[Npad,K]^T (+bias,+relu).
template <bool BIAS, bool RELU, bool OUT_HALF>
__global__ __launch_bounds__(256, 4)
void hgemm_kernel(const _Float16* __restrict__ A, const _Float16* __restrict__ Bt,
                  const float* __restrict__ bias, void* __restrict__ C,
                  int M, int K, int Ncout, int ldc, int gy) {
    __shared__ _Float16 As[128 * 64];   // [row][k], k XOR-swizzled by row&7
    __shared__ _Float16 Bs[64 * 64];

    // m204 bijective XCD-chunked grid map: consecutive wgid (same A-strip)
    // land on one XCD -> A-tile L2 reuse across the gy column-blocks.
    int nwg = gridDim.x;
    int orig = blockIdx.x;
    int q = nwg >> 3, r = nwg & 7;
    int xcd = orig & 7, seq = orig >> 3;
    int wgid = (xcd < r ? xcd * (q + 1) : r * (q + 1) + (xcd - r) * q) + seq;
    int bx = wgid / gy, by = wgid % gy;

    const int tid = threadIdx.x;
    const int wave = tid >> 6, lane = tid & 63;
    const int l15 = lane & 15, lk = lane >> 4;
    const int wr = wave >> 1, wc = wave & 1;   // 2x2: wave = 64 rows x 32 cols
    const int bm = bx * 128, bn = by * 64;

    // staging: chunk c = i*256+tid covers row c>>3 (= i*32 + (tid>>3)),
    // k-group c&7 = tid&7; source k pre-swizzled by row&7 (T2).
    // LDS dest linear at halfs c*8 (wave-uniform base + lane*16B).
    const int sk_swz = (((tid & 7) ^ ((tid >> 3) & 7)) << 3);
    const _Float16* aSrc = A + (size_t)(bm + (tid >> 3)) * K + sk_swz;
    const _Float16* bSrc = Bt + (size_t)(bn + (tid >> 3)) * K + sk_swz;

    const int rowA = wr * 64 + l15;   // + mi*16
    const int rowB = wc * 32 + l15;   // + ni*16
    const int xorK = (l15 & 7) << 3;

    floatx4 acc[4][2] = {};

    const int nt = K >> 6;
    for (int t = 0; t < nt; ++t) {
        int k0 = t << 6;
#pragma unroll
        for (int i = 0; i < 4; ++i)
            gload_lds16(aSrc + k0 + (size_t)i * 32 * K, As + (i * 256 + tid) * 8);
#pragma unroll
        for (int i = 0; i < 2; ++i)
            gload_lds16(bSrc + k0 + (size_t)i * 32 * K, Bs + (i * 256 + tid) * 8);
        __syncthreads();   // drains vmcnt -> tile in LDS
#pragma unroll
        for (int ks = 0; ks < 2; ++ks) {
            const int kidx = ((lk << 3) + (ks << 5)) ^ xorK;
            half8 af[4], bf[2];
#pragma unroll
            for (int mi = 0; mi < 4; ++mi)
                af[mi] = *(const half8*)(&As[(rowA + mi * 16) * 64 + kidx]);
#pragma unroll
            for (int ni = 0; ni < 2; ++ni)
                bf[ni] = *(const half8*)(&Bs[(rowB + ni * 16) * 64 + kidx]);
#pragma unroll
            for (int mi = 0; mi < 4; ++mi)
#pragma unroll
                for (int ni = 0; ni < 2; ++ni)
                    acc[mi][ni] = __builtin_amdgcn_mfma_f32_16x16x32_f16(
                        af[mi], bf[ni], acc[mi][ni], 0, 0, 0);
        }
        __syncthreads();
    }

    // epilogue: C/D layout col=lane&15, row=(lane>>4)*4+reg
#pragma unroll
    for (int mi = 0; mi < 4; ++mi) {
#pragma unroll
        for (int ni = 0; ni < 2; ++ni) {
            int col = bn + wc * 32 + ni * 16 + l15;
            int row0 = bm + wr * 64 + mi * 16 + lk * 4;
            floatx4 vv = acc[mi][ni];
            if (BIAS) {
                float bb = (col < Ncout) ? bias[col] : 0.f;
                vv[0] += bb; vv[1] += bb; vv[2] += bb; vv[3] += bb;
            }
            if (RELU) {
                vv[0] = fmaxf(vv[0], 0.f); vv[1] = fmaxf(vv[1], 0.f);
                vv[2] = fmaxf(vv[2], 0.f); vv[3] = fmaxf(vv[3], 0.f);
            }
            if (col < Ncout) {
#pragma unroll
                for (int rr = 0; rr < 4; ++rr) {
                    int row = row0 + rr;
                    if (row < M) {
                        if (OUT_HALF)
                            ((__half*)C)[(size_t)row * ldc + col] = __float2half(vv[rr]);
                        else
                            ((float*)C)[(size_t)row * ldc + col] = vv[rr];
                    }
                }
            }
        }
    }
}

extern "C" void kernel_launch(void* const* d_in, const int* in_sizes, int n_in,
                              void* d_out, int out_size, void* d_ws, size_t ws_size,
                              hipStream_t stream) {
    const float* x  = (const float*)d_in[0];
    const int*   ei = (const int*)d_in[1];
    const float* W1 = (const float*)d_in[2];
    const float* b1 = (const float*)d_in[3];
    const float* W2 = (const float*)d_in[4];
    const float* b2 = (const float*)d_in[5];
    const float* W3 = (const float*)d_in[6];
    const float* b3 = (const float*)d_in[7];
    const float* Wc = (const float*)d_in[8];
    const float* bc = (const float*)d_in[9];
    float* out = (float*)d_out;

    const int n = in_sizes[0] / 256;   // 20000
    const int E = in_sizes[1] / 2;     // 320000
    const int* src = ei;
    const int* dst = ei + E;
    const int Mpad = ((n + 127) / 128) * 128;  // 20096
    const int gx = Mpad / 128;                 // 157

    size_t off = 0;
    auto take = [&](size_t bytes) -> void* {
        void* p = (char*)d_ws + off;
        off += (bytes + 255) & ~(size_t)255;
        return p;
    };
    float* isd     = (float*)take((size_t)n * 4);
    int*   cnt     = (int*)take((size_t)n * 4);
    int*   pos     = (int*)take((size_t)n * 4);
    int*   row_ptr = (int*)take((size_t)(n + 1) * 4);
    int*   s_src   = (int*)take((size_t)E * 4);
    float* s_nrm   = (float*)take((size_t)E * 4);
    _Float16* xh   = (_Float16*)take((size_t)n * 256 * 2);
    _Float16* a1h  = (_Float16*)take((size_t)Mpad * 256 * 2);
    _Float16* h1h  = (_Float16*)take((size_t)Mpad * 1024 * 2);
    _Float16* g2h  = (_Float16*)take((size_t)Mpad * 512 * 2);
    _Float16* a2h  = (_Float16*)take((size_t)Mpad * 512 * 2);
    _Float16* g3h  = (_Float16*)take((size_t)Mpad * 128 * 2);
    _Float16* a3h  = (_Float16*)take((size_t)Mpad * 128 * 2);
    _Float16* w1t  = (_Float16*)take((size_t)1024 * 256 * 2);
    _Float16* w2t  = (_Float16*)take((size_t)512 * 1024 * 2);
    _Float16* w3t  = (_Float16*)take((size_t)128 * 512 * 2);
    _Float16* wct  = (_Float16*)take((size_t)64 * 128 * 2);

    // --- graph prep ---
    init_kernel<<<(n + 255) / 256, 256, 0, stream>>>(cnt, pos, n);
    hist_kernel<<<(E + 255) / 256, 256, 0, stream>>>(dst, cnt, E);
    isd_kernel<<<(n + 255) / 256, 256, 0, stream>>>(cnt, isd, n);
    scan_kernel<<<1, 1024, 0, stream>>>(cnt, row_ptr, n, E);
    place_kernel<<<(E + 255) / 256, 256, 0, stream>>>(src, dst, isd, row_ptr, pos,
                                                      s_src, s_nrm, E);

    // --- conversions ---
    int n4 = n * 256 / 4;
    f2h_kernel<<<(n4 + 255) / 256, 256, 0, stream>>>((const float4*)x, (half4*)xh, n4);
    wtrans_kernel<<<(1024 * 256 + 255) / 256, 256, 0, stream>>>(W1, w1t, 256, 1024, 1024);
    wtrans_kernel<<<(512 * 1024 + 255) / 256, 256, 0, stream>>>(W2, w2t, 1024, 512, 512);
    wtrans_kernel<<<(128 * 512 + 255) / 256, 256, 0, stream>>>(W3, w3t, 512, 128, 128);
    wtrans_kernel<<<(64 * 128 + 255) / 256, 256, 0, stream>>>(Wc, wct, 128, 64, 64);

    // --- Layer 1: agg(xh)[256] -> GEMM(W1)+b1+relu -> h1h [n,1024] ---
    aggv_kernel<32, false><<<(n * 32 + 255) / 256, 256, 0, stream>>>(
        (const half8*)xh, (half8*)a1h, row_ptr, s_src, s_nrm, isd, nullptr, n);
    hgemm_kernel<true, true, true><<<gx * 16, 256, 0, stream>>>(
        a1h, w1t, b1, h1h, n, 256, 1024, 1024, 16);

    // --- Layer 2: GEMM(W2) -> agg[512]+b2+relu -> a2h ---
    hgemm_kernel<false, false, true><<<gx * 8, 256, 0, stream>>>(
        h1h, w2t, nullptr, g2h, n, 1024, 512, 512, 8);
    aggv_kernel<64, true><<<(n * 64 + 255) / 256, 256, 0, stream>>>(
        (const half8*)g2h, (half8*)a2h, row_ptr, s_src, s_nrm, isd, b2, n);

    // --- Layer 3: GEMM(W3) -> agg[128]+b3+relu -> a3h ---
    hgemm_kernel<false, false, true><<<gx * 2, 256, 0, stream>>>(
        a2h, w3t, nullptr, g3h, n, 512, 128, 128, 2);
    aggv_kernel<16, true><<<(n * 16 + 255) / 256, 256, 0, stream>>>(
        (const half8*)g3h, (half8*)a3h, row_ptr, s_src, s_nrm, isd, b3, n);

    // --- Classifier: GEMM(Wc)+bc -> out [n,64] fp32 ---
    hgemm_kernel<true, false, false><<<gx * 1, 256, 0, stream>>>(
        a3h, wct, bc, out, n, 128, 64, 64, 1);
}